// Round 2
// baseline (2365.436 us; speedup 1.0000x reference)
//
#include <hip/hip_runtime.h>
#include <math.h>

// RALALinearAttention on MI355X — round 2: correct fp32 baseline, batch-passed
// to keep d_ws usage ~70 MiB (round-1 crash suspected d_ws overflow at 343 MiB).
// B=16, H=W=64, C=256, NH=8, HD=32, N=4096. Process BPP=4 batches per pass.
constexpr int B   = 16;
constexpr int IH  = 64;
constexpr int IW  = 64;
constexpr int C   = 256;
constexpr int NH  = 8;
constexpr int HD  = 32;
constexpr int N   = IH * IW;    // 4096
constexpr int C4  = 4 * C;      // 1024
constexpr int BPP = 4;          // batches per pass
constexpr int PN  = BPP * N;    // 16384 rows per pass

// ---------------------------------------------------------------- tables ----
__global__ void k_tables(float* __restrict__ cosT, float* __restrict__ sinT) {
  int t = blockIdx.x * 256 + threadIdx.x;      // N*16 = 65536
  int j = t & 15, pix = t >> 4;
  int y = pix >> 6, x = pix & 63;
  int jj = j & 7;
  double theta = pow(10000.0, -(double)jj / 8.0);
  double pos = (j < 8) ? (double)y : (double)x;
  double ang = pos * theta;
  cosT[t] = (float)cos(ang);
  sinT[t] = (float)sin(ang);
}

// ------------------------------------------------- GEMM1: qkvo = x@W + b ----
// rows are pass-local [0,PN); x offset by b0*N rows. elu+1 fused on cols<512.
__global__ __launch_bounds__(256) void k_gemm_qkvo(
    const float* __restrict__ x, const float* __restrict__ w,
    const float* __restrict__ bias, float* __restrict__ qkvo, int b0) {
  __shared__ float As[16][68];
  __shared__ float Bs[16][64];
  int m0 = blockIdx.x * 64;                    // pass-local row
  int n0 = blockIdx.y * 64;
  int t = threadIdx.x;
  int ty = t >> 4, tx = t & 15;
  float acc[4][4] = {};
  for (int kc = 0; kc < 256; kc += 16) {
    {
      int row = t >> 2, c4 = (t & 3) << 2;
      float4 a4 = *reinterpret_cast<const float4*>(
          &x[(size_t)(b0 * N + m0 + row) * 256 + kc + c4]);
      As[c4 + 0][row] = a4.x; As[c4 + 1][row] = a4.y;
      As[c4 + 2][row] = a4.z; As[c4 + 3][row] = a4.w;
    }
    {
      int row = t >> 4, c4 = (t & 15) << 2;
      *reinterpret_cast<float4*>(&Bs[row][c4]) =
          *reinterpret_cast<const float4*>(&w[(size_t)(kc + row) * C4 + n0 + c4]);
    }
    __syncthreads();
#pragma unroll
    for (int kk = 0; kk < 16; ++kk) {
      float4 a = *reinterpret_cast<const float4*>(&As[kk][ty << 2]);
      float4 b = *reinterpret_cast<const float4*>(&Bs[kk][tx << 2]);
      float av[4] = {a.x, a.y, a.z, a.w};
      float bv[4] = {b.x, b.y, b.z, b.w};
#pragma unroll
      for (int j = 0; j < 4; ++j)
#pragma unroll
        for (int i = 0; i < 4; ++i)
          acc[j][i] = fmaf(av[j], bv[i], acc[j][i]);
    }
    __syncthreads();
  }
  int col = n0 + (tx << 2);
  bool do_elu = col < 512;                  // q and k columns
  float4 bb = *reinterpret_cast<const float4*>(&bias[col]);
#pragma unroll
  for (int j = 0; j < 4; ++j) {
    float4 o;
    o.x = acc[j][0] + bb.x; o.y = acc[j][1] + bb.y;
    o.z = acc[j][2] + bb.z; o.w = acc[j][3] + bb.w;
    if (do_elu) {                           // elu(x)+1 = x+1 (x>0) else exp(x)
      o.x = (o.x > 0.f) ? o.x + 1.f : expf(o.x);
      o.y = (o.y > 0.f) ? o.y + 1.f : expf(o.y);
      o.z = (o.z > 0.f) ? o.z + 1.f : expf(o.z);
      o.w = (o.w > 0.f) ? o.w + 1.f : expf(o.w);
    }
    *reinterpret_cast<float4*>(&qkvo[(size_t)(m0 + (ty << 2) + j) * C4 + col]) = o;
  }
}

// --------------------------------- column-mean over n (q_mean / k_mean) -----
// one block per pass-local (b,h); deterministic tree reduction.
__global__ __launch_bounds__(256) void k_colmean(
    const float* __restrict__ qkvo, const float* __restrict__ effN,
    float* __restrict__ outm, int colbase) {
  int bh = blockIdx.x;                         // [0, BPP*NH)
  int b = bh >> 3, h = bh & 7;
  int t = threadIdx.x;
  int d = t & 31, r = t >> 5;
  size_t base = (size_t)b * N * C4 + colbase + (h << 5) + d;
  float acc = 0.f;
  for (int n = r; n < N; n += 8) {
    float v = qkvo[base + (size_t)n * C4];
    if (effN) v *= effN[(size_t)bh * N + n];
    acc += v;
  }
  __shared__ float sm[256];
  sm[t] = acc;
  __syncthreads();
  if (t < 32) {
    float s = 0.f;
#pragma unroll
    for (int rr = 0; rr < 8; ++rr) s += sm[rr * 32 + t];
    outm[(bh << 5) + t] = s * (1.0f / N);
  }
}

// ------------------------------------------- scores s = scale * qmean.k -----
__global__ void k_scores(const float* __restrict__ qkvo,
                         const float* __restrict__ qmean, float* __restrict__ s) {
  int tid = blockIdx.x * 256 + threadIdx.x;   // BPP*NH*N
  int n = tid & (N - 1);
  int bh = tid >> 12;
  int b = bh >> 3, h = bh & 7;
  const float* kp = &qkvo[(size_t)(b * N + n) * C4 + 256 + (h << 5)];
  const float* qm = &qmean[bh << 5];
  float dot = 0.f;
#pragma unroll
  for (int i = 0; i < 8; ++i) {
    float4 k4 = *reinterpret_cast<const float4*>(&kp[i << 2]);
    float4 q4 = *reinterpret_cast<const float4*>(&qm[i << 2]);
    dot += k4.x * q4.x + k4.y * q4.y + k4.z * q4.z + k4.w * q4.w;
  }
  s[tid] = dot * 0.1767766952966369f;         // 32^-0.5
}

// --------------------------------- softmax over n, fold *N (eff -> eff*N) ---
__global__ __launch_bounds__(256) void k_softmax(float* __restrict__ s) {
  int bh = blockIdx.x;
  int t = threadIdx.x;
  float* row = s + (size_t)bh * N;
  __shared__ float sm[256];
  float mx = -3.4e38f;
  for (int n = t; n < N; n += 256) mx = fmaxf(mx, row[n]);
  sm[t] = mx; __syncthreads();
  for (int off = 128; off > 0; off >>= 1) {
    if (t < off) sm[t] = fmaxf(sm[t], sm[t + off]);
    __syncthreads();
  }
  mx = sm[0]; __syncthreads();
  float sum = 0.f;
  for (int n = t; n < N; n += 256) sum += expf(row[n] - mx);
  sm[t] = sum; __syncthreads();
  for (int off = 128; off > 0; off >>= 1) {
    if (t < off) sm[t] += sm[t + off];
    __syncthreads();
  }
  float scale = (float)N / sm[0];
  for (int n = t; n < N; n += 256) row[n] = expf(row[n] - mx) * scale;
}

// ---------------- z + scale k by eff*N + RoPE(q,k) in place + write z -------
__global__ __launch_bounds__(256) void k_rope_z(
    float* __restrict__ qkvo, const float* __restrict__ effN,
    const float* __restrict__ kmean, const float* __restrict__ cosT,
    const float* __restrict__ sinT, float* __restrict__ z) {
  int tid = blockIdx.x * 256 + threadIdx.x;   // BPP*N*NH
  int h = tid & 7;
  int bn = tid >> 3;                          // pass-local row
  int n = bn & (N - 1);
  int b = bn >> 12;
  size_t qb = (size_t)bn * C4 + (h << 5);
  float q[32], k[32];
#pragma unroll
  for (int i = 0; i < 8; ++i) {
    float4 q4 = *reinterpret_cast<const float4*>(&qkvo[qb + (i << 2)]);
    float4 k4 = *reinterpret_cast<const float4*>(&qkvo[qb + 256 + (i << 2)]);
    q[i * 4 + 0] = q4.x; q[i * 4 + 1] = q4.y; q[i * 4 + 2] = q4.z; q[i * 4 + 3] = q4.w;
    k[i * 4 + 0] = k4.x; k[i * 4 + 1] = k4.y; k[i * 4 + 2] = k4.z; k[i * 4 + 3] = k4.w;
  }
  int bh = (b << 3) + h;
  const float* km = &kmean[bh << 5];
  float dot = 0.f;
#pragma unroll
  for (int dd = 0; dd < 32; ++dd) dot += q[dd] * km[dd];
  z[(size_t)bh * N + n] = 1.0f / (dot + 1e-6f);
  float ef = effN[(size_t)bh * N + n];
#pragma unroll
  for (int dd = 0; dd < 32; ++dd) k[dd] *= ef;
  const float* cp = &cosT[n << 4];
  const float* sp = &sinT[n << 4];
#pragma unroll
  for (int j = 0; j < 16; ++j) {
    float cc = cp[j], ss = sp[j];
    float qr = q[2 * j], qi = q[2 * j + 1];
    q[2 * j]     = qr * cc - qi * ss;
    q[2 * j + 1] = qr * ss + qi * cc;
    float kr = k[2 * j], ki = k[2 * j + 1];
    k[2 * j]     = kr * cc - ki * ss;
    k[2 * j + 1] = kr * ss + ki * cc;
  }
#pragma unroll
  for (int i = 0; i < 8; ++i) {
    float4 q4 = {q[i * 4 + 0], q[i * 4 + 1], q[i * 4 + 2], q[i * 4 + 3]};
    float4 k4 = {k[i * 4 + 0], k[i * 4 + 1], k[i * 4 + 2], k[i * 4 + 3]};
    *reinterpret_cast<float4*>(&qkvo[qb + (i << 2)]) = q4;
    *reinterpret_cast<float4*>(&qkvo[qb + 256 + (i << 2)]) = k4;
  }
}

// ------------------------- kv partials: per (b,h,chunk) 32x32 outer sum -----
__global__ __launch_bounds__(256) void k_kv_partial(
    const float* __restrict__ qkvo, float* __restrict__ kvp) {
  __shared__ float kt[32][33];
  __shared__ float vt[32][33];
  int bh = blockIdx.x, chunk = blockIdx.y;
  int b = bh >> 3, h = bh & 7;
  int t = threadIdx.x;
  int lrow = t >> 3, lc4 = (t & 7) << 2;
  int d = t >> 3, e0 = (t & 7) << 2;
  float a0 = 0, a1 = 0, a2 = 0, a3 = 0;
  int n_start = chunk << 9;                    // 512 per chunk
  for (int n0 = n_start; n0 < n_start + 512; n0 += 32) {
    size_t g = (size_t)(b * N + n0 + lrow) * C4 + (h << 5) + lc4;
    float4 k4 = *reinterpret_cast<const float4*>(&qkvo[g + 256]);
    float4 v4 = *reinterpret_cast<const float4*>(&qkvo[g + 512]);
    kt[lrow][lc4 + 0] = k4.x; kt[lrow][lc4 + 1] = k4.y;
    kt[lrow][lc4 + 2] = k4.z; kt[lrow][lc4 + 3] = k4.w;
    vt[lrow][lc4 + 0] = v4.x; vt[lrow][lc4 + 1] = v4.y;
    vt[lrow][lc4 + 2] = v4.z; vt[lrow][lc4 + 3] = v4.w;
    __syncthreads();
#pragma unroll
    for (int nn = 0; nn < 32; ++nn) {
      float kd = kt[nn][d];
      a0 = fmaf(kd, vt[nn][e0 + 0], a0);
      a1 = fmaf(kd, vt[nn][e0 + 1], a1);
      a2 = fmaf(kd, vt[nn][e0 + 2], a2);
      a3 = fmaf(kd, vt[nn][e0 + 3], a3);
    }
    __syncthreads();
  }
  size_t o = (size_t)(bh * 8 + chunk) * 1024 + (d << 5) + e0;
  kvp[o + 0] = a0; kvp[o + 1] = a1; kvp[o + 2] = a2; kvp[o + 3] = a3;
}

__global__ void k_kv_reduce(const float* __restrict__ kvp, float* __restrict__ kv) {
  int i = blockIdx.x * 256 + threadIdx.x;     // BPP*NH*1024
  int bh = i >> 10, de = i & 1023;
  float s = 0.f;
#pragma unroll
  for (int c = 0; c < 8; ++c) s += kvp[(size_t)(bh * 8 + c) * 1024 + de];
  kv[i] = s * (1.0f / N);                     // fold inv_sqrt_n^2
}

// -------- depthwise 5x5 conv on v (LEPE) -> staged into d_out rows ----------
__global__ __launch_bounds__(256) void k_lepe(
    const float* __restrict__ qkvo, const float* __restrict__ wgt,
    const float* __restrict__ lb, float* __restrict__ lepe_out, int b0) {
  int blk = blockIdx.x;                        // BPP*64*4
  int b = blk >> 8, rem = blk & 255;
  int y = rem >> 2, x0 = (rem & 3) << 4;       // 16 pixels along x
  int c = threadIdx.x;
  float w[25];
#pragma unroll
  for (int i = 0; i < 25; ++i) w[i] = wgt[c * 25 + i];
  float bias = lb[c];
  float acc[16];
#pragma unroll
  for (int p = 0; p < 16; ++p) acc[p] = bias;
#pragma unroll
  for (int dy = 0; dy < 5; ++dy) {
    int yy = y + dy - 2;
    if (yy < 0 || yy >= IH) continue;
    size_t rowb = (size_t)(b * N + (yy << 6)) * C4 + 512 + c;
#pragma unroll
    for (int dx = 0; dx < 5; ++dx) {
      float wv = w[dy * 5 + dx];
#pragma unroll
      for (int p = 0; p < 16; ++p) {
        int xx = x0 + p + dx - 2;
        if (xx < 0 || xx >= IW) continue;
        acc[p] = fmaf(qkvo[rowb + (size_t)xx * C4], wv, acc[p]);
      }
    }
  }
#pragma unroll
  for (int p = 0; p < 16; ++p)
    lepe_out[(size_t)((b0 + b) * N + (y << 6) + x0 + p) * C + c] = acc[p];
}

// ---- opre = ((q_rope @ kv) * z + lepe) * o  -> written into qkvo q-slot ----
// each thread reads its own head's 32 q values into registers first, then
// overwrites those exact 32 slots -> race-free.
__global__ __launch_bounds__(256) void k_out_combine(
    float* __restrict__ qkvo, const float* __restrict__ kv,
    const float* __restrict__ z, const float* __restrict__ lepe, int b0) {
  __shared__ float kvs[1024];
  int bh = blockIdx.x, chunk = blockIdx.y;
  int b = bh >> 3, h = bh & 7;
  int t = threadIdx.x;
  reinterpret_cast<float4*>(kvs)[t] =
      reinterpret_cast<const float4*>(&kv[(size_t)bh << 10])[t];
  __syncthreads();
  int n = (chunk << 8) + t;
  size_t rowbase = (size_t)(b * N + n) * C4;
  float q[32];
#pragma unroll
  for (int i = 0; i < 8; ++i) {
    float4 q4 = *reinterpret_cast<const float4*>(&qkvo[rowbase + (h << 5) + (i << 2)]);
    q[i * 4 + 0] = q4.x; q[i * 4 + 1] = q4.y; q[i * 4 + 2] = q4.z; q[i * 4 + 3] = q4.w;
  }
  float zv = z[(size_t)bh * N + n];
  size_t oc = (size_t)((b0 + b) * N + n) * C + (h << 5);   // lepe rows in d_out
#pragma unroll
  for (int e4 = 0; e4 < 8; ++e4) {
    float ax = 0, ay = 0, az = 0, aw = 0;
#pragma unroll
    for (int dd = 0; dd < 32; ++dd) {
      float4 kv4 = *reinterpret_cast<const float4*>(&kvs[(dd << 5) + (e4 << 2)]);
      float qd = q[dd];
      ax = fmaf(qd, kv4.x, ax); ay = fmaf(qd, kv4.y, ay);
      az = fmaf(qd, kv4.z, az); aw = fmaf(qd, kv4.w, aw);
    }
    float4 lp = *reinterpret_cast<const float4*>(&lepe[oc + (e4 << 2)]);
    float4 ov = *reinterpret_cast<const float4*>(
        &qkvo[rowbase + 768 + (h << 5) + (e4 << 2)]);
    float4 r;
    r.x = (ax * zv + lp.x) * ov.x;
    r.y = (ay * zv + lp.y) * ov.y;
    r.z = (az * zv + lp.z) * ov.z;
    r.w = (aw * zv + lp.w) * ov.w;
    *reinterpret_cast<float4*>(&qkvo[rowbase + (h << 5) + (e4 << 2)]) = r;
  }
}

// ----------- GEMM2: out = opre @ w_proj + b  (opre in qkvo q-slot) ----------
__global__ __launch_bounds__(256) void k_gemm_proj(
    const float* __restrict__ qkvo, const float* __restrict__ w,
    const float* __restrict__ bias, float* __restrict__ out, int b0) {
  __shared__ float As[16][68];
  __shared__ float Bs[16][256];
  int m0 = blockIdx.x * 64;                    // pass-local row
  int t = threadIdx.x;
  int ty = t >> 4, tx = t & 15;
  float acc[4][4][4] = {};
  for (int kc = 0; kc < 256; kc += 16) {
    {
      int row = t >> 2, c4 = (t & 3) << 2;
      float4 a4 = *reinterpret_cast<const float4*>(
          &qkvo[(size_t)(m0 + row) * C4 + kc + c4]);   // stride C4: q-slot
      As[c4 + 0][row] = a4.x; As[c4 + 1][row] = a4.y;
      As[c4 + 2][row] = a4.z; As[c4 + 3][row] = a4.w;
    }
    {
      int r0 = t >> 6, c4 = (t & 63) << 2;
#pragma unroll
      for (int i = 0; i < 4; ++i) {
        int row = r0 + (i << 2);
        *reinterpret_cast<float4*>(&Bs[row][c4]) =
            *reinterpret_cast<const float4*>(&w[(size_t)(kc + row) * 256 + c4]);
      }
    }
    __syncthreads();
#pragma unroll
    for (int kk = 0; kk < 16; ++kk) {
      float4 a = *reinterpret_cast<const float4*>(&As[kk][ty << 2]);
      float av[4] = {a.x, a.y, a.z, a.w};
#pragma unroll
      for (int i = 0; i < 4; ++i) {
        float4 bq = *reinterpret_cast<const float4*>(&Bs[kk][(tx << 2) + (i << 6)]);
        float bv[4] = {bq.x, bq.y, bq.z, bq.w};
#pragma unroll
        for (int j = 0; j < 4; ++j) {
          acc[j][i][0] = fmaf(av[j], bv[0], acc[j][i][0]);
          acc[j][i][1] = fmaf(av[j], bv[1], acc[j][i][1]);
          acc[j][i][2] = fmaf(av[j], bv[2], acc[j][i][2]);
          acc[j][i][3] = fmaf(av[j], bv[3], acc[j][i][3]);
        }
      }
    }
    __syncthreads();
  }
#pragma unroll
  for (int j = 0; j < 4; ++j)
#pragma unroll
    for (int i = 0; i < 4; ++i) {
      int col = (tx << 2) + (i << 6);
      float4 bb = *reinterpret_cast<const float4*>(&bias[col]);
      float4 r;
      r.x = acc[j][i][0] + bb.x; r.y = acc[j][i][1] + bb.y;
      r.z = acc[j][i][2] + bb.z; r.w = acc[j][i][3] + bb.w;
      *reinterpret_cast<float4*>(
          &out[(size_t)(b0 * N + m0 + (ty << 2) + j) * 256 + col]) = r;
    }
}

// ---------------------------------------------------------------------------
extern "C" void kernel_launch(void* const* d_in, const int* in_sizes, int n_in,
                              void* d_out, int out_size, void* d_ws, size_t ws_size,
                              hipStream_t stream) {
  const float* x      = (const float*)d_in[0];
  const float* w_qkvo = (const float*)d_in[1];
  const float* b_qkvo = (const float*)d_in[2];
  const float* lepe_w = (const float*)d_in[3];
  const float* lepe_b = (const float*)d_in[4];
  const float* w_proj = (const float*)d_in[5];
  const float* b_proj = (const float*)d_in[6];
  float* out = (float*)d_out;
  float* ws  = (float*)d_ws;

  // workspace layout (floats) — per-pass buffers, ~70 MiB total
  float* qkvo  = ws;                                  // PN*C4 = 16,777,216
  float* qmean = qkvo  + (size_t)PN * C4;             // 1024
  float* kmean = qmean + BPP * NH * HD;               // 1024
  float* eff   = kmean + BPP * NH * HD;               // 131072
  float* zbuf  = eff   + (size_t)BPP * NH * N;        // 131072
  float* kvp   = zbuf  + (size_t)BPP * NH * N;        // 262144
  float* kv    = kvp   + (size_t)BPP * NH * 1024 * 8; // 32768
  float* cosT  = kv    + (size_t)BPP * NH * 1024;     // 65536
  float* sinT  = cosT  + (size_t)N * 16;              // 65536

  k_tables<<<N * 16 / 256, 256, 0, stream>>>(cosT, sinT);

  for (int b0 = 0; b0 < B; b0 += BPP) {
    k_gemm_qkvo<<<dim3(PN / 64, C4 / 64), 256, 0, stream>>>(x, w_qkvo, b_qkvo, qkvo, b0);
    k_colmean<<<BPP * NH, 256, 0, stream>>>(qkvo, nullptr, qmean, 0);
    k_scores<<<(BPP * NH * N) / 256, 256, 0, stream>>>(qkvo, qmean, eff);
    k_softmax<<<BPP * NH, 256, 0, stream>>>(eff);
    k_colmean<<<BPP * NH, 256, 0, stream>>>(qkvo, eff, kmean, 256);
    k_rope_z<<<(BPP * N * NH) / 256, 256, 0, stream>>>(qkvo, eff, kmean, cosT, sinT, zbuf);
    k_kv_partial<<<dim3(BPP * NH, 8), 256, 0, stream>>>(qkvo, kvp);
    k_kv_reduce<<<(BPP * NH * 1024) / 256, 256, 0, stream>>>(kvp, kv);
    k_lepe<<<BPP * IH * 4, 256, 0, stream>>>(qkvo, lepe_w, lepe_b, out, b0);
    k_out_combine<<<dim3(BPP * NH, N / 256), 256, 0, stream>>>(qkvo, kv, zbuf, out, b0);
    k_gemm_proj<<<PN / 64, 256, 0, stream>>>(qkvo, w_proj, b_proj, out, b0);
  }
}

// Round 3
// 1082.641 us; speedup vs baseline: 2.1849x; 2.1849x over previous
//
#include <hip/hip_runtime.h>
#include <math.h>

// RALALinearAttention on MI355X — round 3.
// Fix: k_colmean was 56% of runtime (32 blocks, 1.4% occupancy, 52 GB/s).
// -> two-stage tree reduction (512-2048 blocks). LDS-cached softmax.
// Adaptive batches-per-pass from ws_size (never exceed the workspace).
constexpr int B   = 16;
constexpr int IH  = 64;
constexpr int IW  = 64;
constexpr int C   = 256;
constexpr int NH  = 8;
constexpr int HD  = 32;
constexpr int N   = IH * IW;    // 4096
constexpr int C4  = 4 * C;      // 1024

// ---------------------------------------------------------------- tables ----
__global__ void k_tables(float* __restrict__ cosT, float* __restrict__ sinT) {
  int t = blockIdx.x * 256 + threadIdx.x;      // N*16 = 65536
  int j = t & 15, pix = t >> 4;
  int y = pix >> 6, x = pix & 63;
  int jj = j & 7;
  double theta = pow(10000.0, -(double)jj / 8.0);
  double pos = (j < 8) ? (double)y : (double)x;
  double ang = pos * theta;
  cosT[t] = (float)cos(ang);
  sinT[t] = (float)sin(ang);
}

// ------------------------------------------------- GEMM1: qkvo = x@W + b ----
__global__ __launch_bounds__(256) void k_gemm_qkvo(
    const float* __restrict__ x, const float* __restrict__ w,
    const float* __restrict__ bias, float* __restrict__ qkvo, int b0) {
  __shared__ float As[16][68];
  __shared__ float Bs[16][64];
  int m0 = blockIdx.x * 64;                    // pass-local row
  int n0 = blockIdx.y * 64;
  int t = threadIdx.x;
  int ty = t >> 4, tx = t & 15;
  float acc[4][4] = {};
  for (int kc = 0; kc < 256; kc += 16) {
    {
      int row = t >> 2, c4 = (t & 3) << 2;
      float4 a4 = *reinterpret_cast<const float4*>(
          &x[(size_t)(b0 * N + m0 + row) * 256 + kc + c4]);
      As[c4 + 0][row] = a4.x; As[c4 + 1][row] = a4.y;
      As[c4 + 2][row] = a4.z; As[c4 + 3][row] = a4.w;
    }
    {
      int row = t >> 4, c4 = (t & 15) << 2;
      *reinterpret_cast<float4*>(&Bs[row][c4]) =
          *reinterpret_cast<const float4*>(&w[(size_t)(kc + row) * C4 + n0 + c4]);
    }
    __syncthreads();
#pragma unroll
    for (int kk = 0; kk < 16; ++kk) {
      float4 a = *reinterpret_cast<const float4*>(&As[kk][ty << 2]);
      float4 b = *reinterpret_cast<const float4*>(&Bs[kk][tx << 2]);
      float av[4] = {a.x, a.y, a.z, a.w};
      float bv[4] = {b.x, b.y, b.z, b.w};
#pragma unroll
      for (int j = 0; j < 4; ++j)
#pragma unroll
        for (int i = 0; i < 4; ++i)
          acc[j][i] = fmaf(av[j], bv[i], acc[j][i]);
    }
    __syncthreads();
  }
  int col = n0 + (tx << 2);
  bool do_elu = col < 512;                  // q and k columns
  float4 bb = *reinterpret_cast<const float4*>(&bias[col]);
#pragma unroll
  for (int j = 0; j < 4; ++j) {
    float4 o;
    o.x = acc[j][0] + bb.x; o.y = acc[j][1] + bb.y;
    o.z = acc[j][2] + bb.z; o.w = acc[j][3] + bb.w;
    if (do_elu) {                           // elu(x)+1 = x+1 (x>0) else exp(x)
      o.x = (o.x > 0.f) ? o.x + 1.f : expf(o.x);
      o.y = (o.y > 0.f) ? o.y + 1.f : expf(o.y);
      o.z = (o.z > 0.f) ? o.z + 1.f : expf(o.z);
      o.w = (o.w > 0.f) ? o.w + 1.f : expf(o.w);
    }
    *reinterpret_cast<float4*>(&qkvo[(size_t)(m0 + (ty << 2) + j) * C4 + col]) = o;
  }
}

// ---------------- column-mean over n, stage 1: per-(bh,chunk) partials ------
// grid (bpp*NH, 16); each block reduces 256 rows -> 32 partials.
__global__ __launch_bounds__(256) void k_colmean_part(
    const float* __restrict__ qkvo, const float* __restrict__ effN,
    float* __restrict__ part, int colbase) {
  int bh = blockIdx.x, chunk = blockIdx.y;
  int b = bh >> 3, h = bh & 7;
  int t = threadIdx.x;
  int d = t & 31, r = t >> 5;                  // 8 rows in flight
  size_t base = (size_t)b * N * C4 + colbase + (h << 5) + d;
  int n0 = chunk << 8;
  float acc = 0.f;
  for (int n = n0 + r; n < n0 + 256; n += 8) {
    float v = qkvo[base + (size_t)n * C4];
    if (effN) v *= effN[(size_t)bh * N + n];
    acc += v;
  }
  __shared__ float sm[256];
  sm[t] = acc;
  __syncthreads();
  if (t < 32) {
    float s = 0.f;
#pragma unroll
    for (int rr = 0; rr < 8; ++rr) s += sm[rr * 32 + t];
    part[(size_t)((bh << 4) + chunk) * 32 + t] = s;
  }
}

// ---------------- column-mean stage 2: combine 16 chunk partials ------------
__global__ void k_colmean_fin(const float* __restrict__ part,
                              float* __restrict__ outm, int total) {
  int i = blockIdx.x * 256 + threadIdx.x;      // bpp*NH*32
  if (i >= total) return;
  int bh = i >> 5, d = i & 31;
  float s = 0.f;
#pragma unroll
  for (int c = 0; c < 16; ++c) s += part[(size_t)((bh << 4) + c) * 32 + d];
  outm[i] = s * (1.0f / N);
}

// ------------------------------------------- scores s = scale * qmean.k -----
__global__ void k_scores(const float* __restrict__ qkvo,
                         const float* __restrict__ qmean, float* __restrict__ s) {
  int tid = blockIdx.x * 256 + threadIdx.x;   // bpp*NH*N
  int n = tid & (N - 1);
  int bh = tid >> 12;
  int b = bh >> 3, h = bh & 7;
  const float* kp = &qkvo[(size_t)(b * N + n) * C4 + 256 + (h << 5)];
  const float* qm = &qmean[bh << 5];
  float dot = 0.f;
#pragma unroll
  for (int i = 0; i < 8; ++i) {
    float4 k4 = *reinterpret_cast<const float4*>(&kp[i << 2]);
    float4 q4 = *reinterpret_cast<const float4*>(&qm[i << 2]);
    dot += k4.x * q4.x + k4.y * q4.y + k4.z * q4.z + k4.w * q4.w;
  }
  s[tid] = dot * 0.1767766952966369f;         // 32^-0.5
}

// ------------- softmax over n (LDS-cached row), fold *N (eff -> eff*N) ------
__global__ __launch_bounds__(256) void k_softmax(float* __restrict__ s) {
  __shared__ float rowl[N];
  __shared__ float red[256];
  int bh = blockIdx.x;
  int t = threadIdx.x;
  float* row = s + (size_t)bh * N;
  float mx = -3.4e38f;
  for (int i = t; i < N / 4; i += 256) {
    float4 v = reinterpret_cast<const float4*>(row)[i];
    reinterpret_cast<float4*>(rowl)[i] = v;
    mx = fmaxf(mx, fmaxf(fmaxf(v.x, v.y), fmaxf(v.z, v.w)));
  }
  red[t] = mx; __syncthreads();
  for (int off = 128; off > 0; off >>= 1) {
    if (t < off) red[t] = fmaxf(red[t], red[t + off]);
    __syncthreads();
  }
  mx = red[0]; __syncthreads();
  float sum = 0.f;
  for (int n = t; n < N; n += 256) {
    float e = expf(rowl[n] - mx);
    rowl[n] = e;
    sum += e;
  }
  red[t] = sum; __syncthreads();
  for (int off = 128; off > 0; off >>= 1) {
    if (t < off) red[t] += red[t + off];
    __syncthreads();
  }
  float scale = (float)N / red[0];
  for (int i = t; i < N / 4; i += 256) {
    float4 v = reinterpret_cast<const float4*>(rowl)[i];
    v.x *= scale; v.y *= scale; v.z *= scale; v.w *= scale;
    reinterpret_cast<float4*>(row)[i] = v;
  }
}

// ---------------- z + scale k by eff*N + RoPE(q,k) in place + write z -------
__global__ __launch_bounds__(256) void k_rope_z(
    float* __restrict__ qkvo, const float* __restrict__ effN,
    const float* __restrict__ kmean, const float* __restrict__ cosT,
    const float* __restrict__ sinT, float* __restrict__ z) {
  int tid = blockIdx.x * 256 + threadIdx.x;   // bpp*N*NH
  int h = tid & 7;
  int bn = tid >> 3;                          // pass-local row
  int n = bn & (N - 1);
  int b = bn >> 12;
  size_t qb = (size_t)bn * C4 + (h << 5);
  float q[32], k[32];
#pragma unroll
  for (int i = 0; i < 8; ++i) {
    float4 q4 = *reinterpret_cast<const float4*>(&qkvo[qb + (i << 2)]);
    float4 k4 = *reinterpret_cast<const float4*>(&qkvo[qb + 256 + (i << 2)]);
    q[i * 4 + 0] = q4.x; q[i * 4 + 1] = q4.y; q[i * 4 + 2] = q4.z; q[i * 4 + 3] = q4.w;
    k[i * 4 + 0] = k4.x; k[i * 4 + 1] = k4.y; k[i * 4 + 2] = k4.z; k[i * 4 + 3] = k4.w;
  }
  int bh = (b << 3) + h;
  const float* km = &kmean[bh << 5];
  float dot = 0.f;
#pragma unroll
  for (int dd = 0; dd < 32; ++dd) dot += q[dd] * km[dd];
  z[(size_t)bh * N + n] = 1.0f / (dot + 1e-6f);
  float ef = effN[(size_t)bh * N + n];
#pragma unroll
  for (int dd = 0; dd < 32; ++dd) k[dd] *= ef;
  const float* cp = &cosT[n << 4];
  const float* sp = &sinT[n << 4];
#pragma unroll
  for (int j = 0; j < 16; ++j) {
    float cc = cp[j], ss = sp[j];
    float qr = q[2 * j], qi = q[2 * j + 1];
    q[2 * j]     = qr * cc - qi * ss;
    q[2 * j + 1] = qr * ss + qi * cc;
    float kr = k[2 * j], ki = k[2 * j + 1];
    k[2 * j]     = kr * cc - ki * ss;
    k[2 * j + 1] = kr * ss + ki * cc;
  }
#pragma unroll
  for (int i = 0; i < 8; ++i) {
    float4 q4 = {q[i * 4 + 0], q[i * 4 + 1], q[i * 4 + 2], q[i * 4 + 3]};
    float4 k4 = {k[i * 4 + 0], k[i * 4 + 1], k[i * 4 + 2], k[i * 4 + 3]};
    *reinterpret_cast<float4*>(&qkvo[qb + (i << 2)]) = q4;
    *reinterpret_cast<float4*>(&qkvo[qb + 256 + (i << 2)]) = k4;
  }
}

// ------------------------- kv partials: per (b,h,chunk) 32x32 outer sum -----
__global__ __launch_bounds__(256) void k_kv_partial(
    const float* __restrict__ qkvo, float* __restrict__ kvp) {
  __shared__ float kt[32][33];
  __shared__ float vt[32][33];
  int bh = blockIdx.x, chunk = blockIdx.y;
  int b = bh >> 3, h = bh & 7;
  int t = threadIdx.x;
  int lrow = t >> 3, lc4 = (t & 7) << 2;
  int d = t >> 3, e0 = (t & 7) << 2;
  float a0 = 0, a1 = 0, a2 = 0, a3 = 0;
  int n_start = chunk << 9;                    // 512 per chunk
  for (int n0 = n_start; n0 < n_start + 512; n0 += 32) {
    size_t g = (size_t)(b * N + n0 + lrow) * C4 + (h << 5) + lc4;
    float4 k4 = *reinterpret_cast<const float4*>(&qkvo[g + 256]);
    float4 v4 = *reinterpret_cast<const float4*>(&qkvo[g + 512]);
    kt[lrow][lc4 + 0] = k4.x; kt[lrow][lc4 + 1] = k4.y;
    kt[lrow][lc4 + 2] = k4.z; kt[lrow][lc4 + 3] = k4.w;
    vt[lrow][lc4 + 0] = v4.x; vt[lrow][lc4 + 1] = v4.y;
    vt[lrow][lc4 + 2] = v4.z; vt[lrow][lc4 + 3] = v4.w;
    __syncthreads();
#pragma unroll
    for (int nn = 0; nn < 32; ++nn) {
      float kd = kt[nn][d];
      a0 = fmaf(kd, vt[nn][e0 + 0], a0);
      a1 = fmaf(kd, vt[nn][e0 + 1], a1);
      a2 = fmaf(kd, vt[nn][e0 + 2], a2);
      a3 = fmaf(kd, vt[nn][e0 + 3], a3);
    }
    __syncthreads();
  }
  size_t o = (size_t)(bh * 8 + chunk) * 1024 + (d << 5) + e0;
  kvp[o + 0] = a0; kvp[o + 1] = a1; kvp[o + 2] = a2; kvp[o + 3] = a3;
}

__global__ void k_kv_reduce(const float* __restrict__ kvp, float* __restrict__ kv,
                            int total) {
  int i = blockIdx.x * 256 + threadIdx.x;     // bpp*NH*1024
  if (i >= total) return;
  int bh = i >> 10, de = i & 1023;
  float s = 0.f;
#pragma unroll
  for (int c = 0; c < 8; ++c) s += kvp[(size_t)(bh * 8 + c) * 1024 + de];
  kv[i] = s * (1.0f / N);                     // fold inv_sqrt_n^2
}

// -------- depthwise 5x5 conv on v (LEPE) -> staged into d_out rows ----------
__global__ __launch_bounds__(256) void k_lepe(
    const float* __restrict__ qkvo, const float* __restrict__ wgt,
    const float* __restrict__ lb, float* __restrict__ lepe_out, int b0) {
  int blk = blockIdx.x;                        // bpp*64*4
  int b = blk >> 8, rem = blk & 255;
  int y = rem >> 2, x0 = (rem & 3) << 4;       // 16 pixels along x
  int c = threadIdx.x;
  float w[25];
#pragma unroll
  for (int i = 0; i < 25; ++i) w[i] = wgt[c * 25 + i];
  float bias = lb[c];
  float acc[16];
#pragma unroll
  for (int p = 0; p < 16; ++p) acc[p] = bias;
#pragma unroll
  for (int dy = 0; dy < 5; ++dy) {
    int yy = y + dy - 2;
    if (yy < 0 || yy >= IH) continue;
    size_t rowb = (size_t)(b * N + (yy << 6)) * C4 + 512 + c;
#pragma unroll
    for (int dx = 0; dx < 5; ++dx) {
      float wv = w[dy * 5 + dx];
#pragma unroll
      for (int p = 0; p < 16; ++p) {
        int xx = x0 + p + dx - 2;
        if (xx < 0 || xx >= IW) continue;
        acc[p] = fmaf(qkvo[rowb + (size_t)xx * C4], wv, acc[p]);
      }
    }
  }
#pragma unroll
  for (int p = 0; p < 16; ++p)
    lepe_out[(size_t)((b0 + b) * N + (y << 6) + x0 + p) * C + c] = acc[p];
}

// ---- opre = ((q_rope @ kv) * z + lepe) * o  -> written into qkvo q-slot ----
__global__ __launch_bounds__(256) void k_out_combine(
    float* __restrict__ qkvo, const float* __restrict__ kv,
    const float* __restrict__ z, const float* __restrict__ lepe, int b0) {
  __shared__ float kvs[1024];
  int bh = blockIdx.x, chunk = blockIdx.y;
  int b = bh >> 3, h = bh & 7;
  int t = threadIdx.x;
  reinterpret_cast<float4*>(kvs)[t] =
      reinterpret_cast<const float4*>(&kv[(size_t)bh << 10])[t];
  __syncthreads();
  int n = (chunk << 8) + t;
  size_t rowbase = (size_t)(b * N + n) * C4;
  float q[32];
#pragma unroll
  for (int i = 0; i < 8; ++i) {
    float4 q4 = *reinterpret_cast<const float4*>(&qkvo[rowbase + (h << 5) + (i << 2)]);
    q[i * 4 + 0] = q4.x; q[i * 4 + 1] = q4.y; q[i * 4 + 2] = q4.z; q[i * 4 + 3] = q4.w;
  }
  float zv = z[(size_t)bh * N + n];
  size_t oc = (size_t)((b0 + b) * N + n) * C + (h << 5);   // lepe rows in d_out
#pragma unroll
  for (int e4 = 0; e4 < 8; ++e4) {
    float ax = 0, ay = 0, az = 0, aw = 0;
#pragma unroll
    for (int dd = 0; dd < 32; ++dd) {
      float4 kv4 = *reinterpret_cast<const float4*>(&kvs[(dd << 5) + (e4 << 2)]);
      float qd = q[dd];
      ax = fmaf(qd, kv4.x, ax); ay = fmaf(qd, kv4.y, ay);
      az = fmaf(qd, kv4.z, az); aw = fmaf(qd, kv4.w, aw);
    }
    float4 lp = *reinterpret_cast<const float4*>(&lepe[oc + (e4 << 2)]);
    float4 ov = *reinterpret_cast<const float4*>(
        &qkvo[rowbase + 768 + (h << 5) + (e4 << 2)]);
    float4 r;
    r.x = (ax * zv + lp.x) * ov.x;
    r.y = (ay * zv + lp.y) * ov.y;
    r.z = (az * zv + lp.z) * ov.z;
    r.w = (aw * zv + lp.w) * ov.w;
    *reinterpret_cast<float4*>(&qkvo[rowbase + (h << 5) + (e4 << 2)]) = r;
  }
}

// ----------- GEMM2: out = opre @ w_proj + b  (opre in qkvo q-slot) ----------
__global__ __launch_bounds__(256) void k_gemm_proj(
    const float* __restrict__ qkvo, const float* __restrict__ w,
    const float* __restrict__ bias, float* __restrict__ out, int b0) {
  __shared__ float As[16][68];
  __shared__ float Bs[16][256];
  int m0 = blockIdx.x * 64;                    // pass-local row
  int t = threadIdx.x;
  int ty = t >> 4, tx = t & 15;
  float acc[4][4][4] = {};
  for (int kc = 0; kc < 256; kc += 16) {
    {
      int row = t >> 2, c4 = (t & 3) << 2;
      float4 a4 = *reinterpret_cast<const float4*>(
          &qkvo[(size_t)(m0 + row) * C4 + kc + c4]);   // stride C4: q-slot
      As[c4 + 0][row] = a4.x; As[c4 + 1][row] = a4.y;
      As[c4 + 2][row] = a4.z; As[c4 + 3][row] = a4.w;
    }
    {
      int r0 = t >> 6, c4 = (t & 63) << 2;
#pragma unroll
      for (int i = 0; i < 4; ++i) {
        int row = r0 + (i << 2);
        *reinterpret_cast<float4*>(&Bs[row][c4]) =
            *reinterpret_cast<const float4*>(&w[(size_t)(kc + row) * 256 + c4]);
      }
    }
    __syncthreads();
#pragma unroll
    for (int kk = 0; kk < 16; ++kk) {
      float4 a = *reinterpret_cast<const float4*>(&As[kk][ty << 2]);
      float av[4] = {a.x, a.y, a.z, a.w};
#pragma unroll
      for (int i = 0; i < 4; ++i) {
        float4 bq = *reinterpret_cast<const float4*>(&Bs[kk][(tx << 2) + (i << 6)]);
        float bv[4] = {bq.x, bq.y, bq.z, bq.w};
#pragma unroll
        for (int j = 0; j < 4; ++j) {
          acc[j][i][0] = fmaf(av[j], bv[0], acc[j][i][0]);
          acc[j][i][1] = fmaf(av[j], bv[1], acc[j][i][1]);
          acc[j][i][2] = fmaf(av[j], bv[2], acc[j][i][2]);
          acc[j][i][3] = fmaf(av[j], bv[3], acc[j][i][3]);
        }
      }
    }
    __syncthreads();
  }
#pragma unroll
  for (int j = 0; j < 4; ++j)
#pragma unroll
    for (int i = 0; i < 4; ++i) {
      int col = (tx << 2) + (i << 6);
      float4 bb = *reinterpret_cast<const float4*>(&bias[col]);
      float4 r;
      r.x = acc[j][i][0] + bb.x; r.y = acc[j][i][1] + bb.y;
      r.z = acc[j][i][2] + bb.z; r.w = acc[j][i][3] + bb.w;
      *reinterpret_cast<float4*>(
          &out[(size_t)(b0 * N + m0 + (ty << 2) + j) * 256 + col]) = r;
    }
}

// ---------------------------------------------------------------------------
static inline size_t ws_floats_needed(int bpp) {
  size_t pn = (size_t)bpp * N;
  return pn * C4                    // qkvo
       + (size_t)bpp * NH * HD * 2  // qmean, kmean
       + (size_t)bpp * NH * N * 2   // eff, z
       + (size_t)bpp * NH * 1024 * 8// kvp
       + (size_t)bpp * NH * 1024    // kv
       + (size_t)bpp * NH * 16 * 32 // colmean partials
       + (size_t)N * 16 * 2;        // cos/sin
}

extern "C" void kernel_launch(void* const* d_in, const int* in_sizes, int n_in,
                              void* d_out, int out_size, void* d_ws, size_t ws_size,
                              hipStream_t stream) {
  const float* x      = (const float*)d_in[0];
  const float* w_qkvo = (const float*)d_in[1];
  const float* b_qkvo = (const float*)d_in[2];
  const float* lepe_w = (const float*)d_in[3];
  const float* lepe_b = (const float*)d_in[4];
  const float* w_proj = (const float*)d_in[5];
  const float* b_proj = (const float*)d_in[6];
  float* out = (float*)d_out;
  float* ws  = (float*)d_ws;

  // pick largest batches-per-pass that fits the workspace
  int bpp = 4;
  if (ws_floats_needed(16) * 4 <= ws_size) bpp = 16;
  else if (ws_floats_needed(8) * 4 <= ws_size) bpp = 8;

  size_t pn = (size_t)bpp * N;
  float* qkvo  = ws;
  float* qmean = qkvo  + pn * C4;
  float* kmean = qmean + (size_t)bpp * NH * HD;
  float* eff   = kmean + (size_t)bpp * NH * HD;
  float* zbuf  = eff   + (size_t)bpp * NH * N;
  float* kvp   = zbuf  + (size_t)bpp * NH * N;
  float* kv    = kvp   + (size_t)bpp * NH * 1024 * 8;
  float* part  = kv    + (size_t)bpp * NH * 1024;
  float* cosT  = part  + (size_t)bpp * NH * 16 * 32;
  float* sinT  = cosT  + (size_t)N * 16;

  k_tables<<<N * 16 / 256, 256, 0, stream>>>(cosT, sinT);

  int nbh = bpp * NH;
  for (int b0 = 0; b0 < B; b0 += bpp) {
    k_gemm_qkvo<<<dim3(pn / 64, C4 / 64), 256, 0, stream>>>(x, w_qkvo, b_qkvo, qkvo, b0);
    k_colmean_part<<<dim3(nbh, 16), 256, 0, stream>>>(qkvo, nullptr, part, 0);
    k_colmean_fin<<<(nbh * 32 + 255) / 256, 256, 0, stream>>>(part, qmean, nbh * 32);
    k_scores<<<(nbh * N) / 256, 256, 0, stream>>>(qkvo, qmean, eff);
    k_softmax<<<nbh, 256, 0, stream>>>(eff);
    k_colmean_part<<<dim3(nbh, 16), 256, 0, stream>>>(qkvo, eff, part, 256);
    k_colmean_fin<<<(nbh * 32 + 255) / 256, 256, 0, stream>>>(part, kmean, nbh * 32);
    k_rope_z<<<(nbh * N) / 256, 256, 0, stream>>>(qkvo, eff, kmean, cosT, sinT, zbuf);
    k_kv_partial<<<dim3(nbh, 8), 256, 0, stream>>>(qkvo, kvp);
    k_kv_reduce<<<(nbh * 1024 + 255) / 256, 256, 0, stream>>>(kvp, kv, nbh * 1024);
    k_lepe<<<bpp * IH * 4, 256, 0, stream>>>(qkvo, lepe_w, lepe_b, out, b0);
    k_out_combine<<<dim3(nbh, N / 256), 256, 0, stream>>>(qkvo, kv, zbuf, out, b0);
    k_gemm_proj<<<pn / 64, 256, 0, stream>>>(qkvo, w_proj, b_proj, out, b0);
  }
}

// Round 4
// 707.004 us; speedup vs baseline: 3.3457x; 1.5313x over previous
//
#include <hip/hip_runtime.h>
#include <math.h>

// RALALinearAttention on MI355X — round 4.
// GEMM1 was 86% of runtime at 36.7 TF on the fp32 VALU pipe (MfmaUtil=0).
// -> split-f16 MFMA GEMM (Ootomo 2-term split, 3 products = fp32-equivalent
//    precision) for both GEMM1 (qkvo) and GEMM2 (proj).
constexpr int B   = 16;
constexpr int IH  = 64;
constexpr int IW  = 64;
constexpr int C   = 256;
constexpr int NH  = 8;
constexpr int HD  = 32;
constexpr int N   = IH * IW;    // 4096
constexpr int C4  = 4 * C;      // 1024

using f16x8 = __attribute__((ext_vector_type(8))) _Float16;
using f32x4 = __attribute__((ext_vector_type(4))) float;
typedef unsigned short ushortT;

// ---------------------------------------------------------------- tables ----
__global__ void k_tables(float* __restrict__ cosT, float* __restrict__ sinT) {
  int t = blockIdx.x * 256 + threadIdx.x;      // N*16 = 65536
  int j = t & 15, pix = t >> 4;
  int y = pix >> 6, x = pix & 63;
  int jj = j & 7;
  double theta = pow(10000.0, -(double)jj / 8.0);
  double pos = (j < 8) ? (double)y : (double)x;
  double ang = pos * theta;
  cosT[t] = (float)cos(ang);
  sinT[t] = (float)sin(ang);
}

// --------------- split-f16 MFMA GEMM: C = A(f32) @ B(f32) + bias ------------
// 128x128 tile, 256 threads (4 waves 2x2), K=256, KSTEP=32.
// A,B converted on the fly to f16 hi/lo (Ootomo split, 3 MFMA products).
// LDS rows padded to 40 ushorts (80B) -> <=2-way conflicts on ds_read_b128.
// nelu: leading columns that get elu(x)+1 fused (512 for GEMM1, 0 for GEMM2).
__global__ __launch_bounds__(256) void k_gemm_mfma(
    const float* __restrict__ A, int lda,
    const float* __restrict__ Bm, int ldb,
    const float* __restrict__ bias, float* __restrict__ Cm, int ldc,
    int nelu) {
  __shared__ ushortT Ah[128 * 40], Al[128 * 40], Bh[128 * 40], Bl[128 * 40];
  int t = threadIdx.x;
  int m0 = blockIdx.x * 128, n0 = blockIdx.y * 128;
  int lane = t & 63;
  int wm = (t >> 6) >> 1, wn = (t >> 6) & 1;   // 2x2 wave grid, 64x64 each
  int lr = lane & 15, lg = lane >> 4;

  // staging coords: A: thread covers 8 k-contiguous f32 (one LDS 8-group)
  int sa_row = t >> 2;            // 0..63 (+64 on second iter)
  int sa_g   = t & 3;             // k-group 0..3 (k0 = g*8)
  // B: thread covers one column, 16 consecutive k
  int sb_col = t & 127;
  int sb_kg  = t >> 7;            // 0..1 -> k = kg*16 + e

  f32x4 acc[4][4] = {};

  for (int kc = 0; kc < 256; kc += 32) {
    // ---- stage A (128 rows x 32 k) ----
#pragma unroll
    for (int i = 0; i < 2; ++i) {
      int row = sa_row + i * 64;
      const float* ap = &A[(size_t)(m0 + row) * lda + kc + sa_g * 8];
      float4 v0 = *reinterpret_cast<const float4*>(ap);
      float4 v1 = *reinterpret_cast<const float4*>(ap + 4);
      float vv[8] = {v0.x, v0.y, v0.z, v0.w, v1.x, v1.y, v1.z, v1.w};
      f16x8 hi, lo;
#pragma unroll
      for (int j = 0; j < 8; ++j) {
        _Float16 h = (_Float16)vv[j];
        hi[j] = h;
        lo[j] = (_Float16)(vv[j] - (float)h);
      }
      *reinterpret_cast<f16x8*>(&Ah[row * 40 + sa_g * 8]) = hi;
      *reinterpret_cast<f16x8*>(&Al[row * 40 + sa_g * 8]) = lo;
    }
    // ---- stage B (32 k x 128 n) ----
    {
      float bv[16];
#pragma unroll
      for (int e = 0; e < 16; ++e)
        bv[e] = Bm[(size_t)(kc + sb_kg * 16 + e) * ldb + n0 + sb_col];
      f16x8 hi0, lo0, hi1, lo1;
#pragma unroll
      for (int e = 0; e < 8; ++e) {
        _Float16 h0 = (_Float16)bv[e];
        hi0[e] = h0; lo0[e] = (_Float16)(bv[e] - (float)h0);
        _Float16 h1 = (_Float16)bv[e + 8];
        hi1[e] = h1; lo1[e] = (_Float16)(bv[e + 8] - (float)h1);
      }
      int ad = sb_col * 40 + sb_kg * 16;
      *reinterpret_cast<f16x8*>(&Bh[ad]) = hi0;
      *reinterpret_cast<f16x8*>(&Bh[ad + 8]) = hi1;
      *reinterpret_cast<f16x8*>(&Bl[ad]) = lo0;
      *reinterpret_cast<f16x8*>(&Bl[ad + 8]) = lo1;
    }
    __syncthreads();

    // ---- fragments + MFMA ----
    f16x8 ah[4], al[4];
#pragma unroll
    for (int mi = 0; mi < 4; ++mi) {
      int arow = wm * 64 + mi * 16 + lr;
      ah[mi] = *reinterpret_cast<const f16x8*>(&Ah[arow * 40 + lg * 8]);
      al[mi] = *reinterpret_cast<const f16x8*>(&Al[arow * 40 + lg * 8]);
    }
#pragma unroll
    for (int ni = 0; ni < 4; ++ni) {
      int bcol = wn * 64 + ni * 16 + lr;
      f16x8 bh = *reinterpret_cast<const f16x8*>(&Bh[bcol * 40 + lg * 8]);
      f16x8 bl = *reinterpret_cast<const f16x8*>(&Bl[bcol * 40 + lg * 8]);
#pragma unroll
      for (int mi = 0; mi < 4; ++mi) {
        acc[mi][ni] = __builtin_amdgcn_mfma_f32_16x16x32_f16(ah[mi], bh, acc[mi][ni], 0, 0, 0);
        acc[mi][ni] = __builtin_amdgcn_mfma_f32_16x16x32_f16(al[mi], bh, acc[mi][ni], 0, 0, 0);
        acc[mi][ni] = __builtin_amdgcn_mfma_f32_16x16x32_f16(ah[mi], bl, acc[mi][ni], 0, 0, 0);
      }
    }
    __syncthreads();
  }

  // ---- epilogue: bias (+ elu on cols < nelu), scattered dword stores ----
#pragma unroll
  for (int ni = 0; ni < 4; ++ni) {
    int col = n0 + wn * 64 + ni * 16 + lr;
    float bb = bias[col];
    bool de = col < nelu;
#pragma unroll
    for (int mi = 0; mi < 4; ++mi) {
#pragma unroll
      for (int r = 0; r < 4; ++r) {
        int row = m0 + wm * 64 + mi * 16 + lg * 4 + r;
        float v = acc[mi][ni][r] + bb;
        if (de) v = (v > 0.f) ? v + 1.f : expf(v);
        Cm[(size_t)row * ldc + col] = v;
      }
    }
  }
}

// ---------------- column-mean over n, stage 1: per-(bh,chunk) partials ------
__global__ __launch_bounds__(256) void k_colmean_part(
    const float* __restrict__ qkvo, const float* __restrict__ effN,
    float* __restrict__ part, int colbase) {
  int bh = blockIdx.x, chunk = blockIdx.y;
  int b = bh >> 3, h = bh & 7;
  int t = threadIdx.x;
  int d = t & 31, r = t >> 5;                  // 8 rows in flight
  size_t base = (size_t)b * N * C4 + colbase + (h << 5) + d;
  int n0 = chunk << 8;
  float acc = 0.f;
  for (int n = n0 + r; n < n0 + 256; n += 8) {
    float v = qkvo[base + (size_t)n * C4];
    if (effN) v *= effN[(size_t)bh * N + n];
    acc += v;
  }
  __shared__ float sm[256];
  sm[t] = acc;
  __syncthreads();
  if (t < 32) {
    float s = 0.f;
#pragma unroll
    for (int rr = 0; rr < 8; ++rr) s += sm[rr * 32 + t];
    part[(size_t)((bh << 4) + chunk) * 32 + t] = s;
  }
}

// ---------------- column-mean stage 2: combine 16 chunk partials ------------
__global__ void k_colmean_fin(const float* __restrict__ part,
                              float* __restrict__ outm, int total) {
  int i = blockIdx.x * 256 + threadIdx.x;      // bpp*NH*32
  if (i >= total) return;
  int bh = i >> 5, d = i & 31;
  float s = 0.f;
#pragma unroll
  for (int c = 0; c < 16; ++c) s += part[(size_t)((bh << 4) + c) * 32 + d];
  outm[i] = s * (1.0f / N);
}

// ------------------------------------------- scores s = scale * qmean.k -----
__global__ void k_scores(const float* __restrict__ qkvo,
                         const float* __restrict__ qmean, float* __restrict__ s) {
  int tid = blockIdx.x * 256 + threadIdx.x;   // bpp*NH*N
  int n = tid & (N - 1);
  int bh = tid >> 12;
  int b = bh >> 3, h = bh & 7;
  const float* kp = &qkvo[(size_t)(b * N + n) * C4 + 256 + (h << 5)];
  const float* qm = &qmean[bh << 5];
  float dot = 0.f;
#pragma unroll
  for (int i = 0; i < 8; ++i) {
    float4 k4 = *reinterpret_cast<const float4*>(&kp[i << 2]);
    float4 q4 = *reinterpret_cast<const float4*>(&qm[i << 2]);
    dot += k4.x * q4.x + k4.y * q4.y + k4.z * q4.z + k4.w * q4.w;
  }
  s[tid] = dot * 0.1767766952966369f;         // 32^-0.5
}

// ------------- softmax over n (LDS-cached row), fold *N (eff -> eff*N) ------
__global__ __launch_bounds__(256) void k_softmax(float* __restrict__ s) {
  __shared__ float rowl[N];
  __shared__ float red[256];
  int bh = blockIdx.x;
  int t = threadIdx.x;
  float* row = s + (size_t)bh * N;
  float mx = -3.4e38f;
  for (int i = t; i < N / 4; i += 256) {
    float4 v = reinterpret_cast<const float4*>(row)[i];
    reinterpret_cast<float4*>(rowl)[i] = v;
    mx = fmaxf(mx, fmaxf(fmaxf(v.x, v.y), fmaxf(v.z, v.w)));
  }
  red[t] = mx; __syncthreads();
  for (int off = 128; off > 0; off >>= 1) {
    if (t < off) red[t] = fmaxf(red[t], red[t + off]);
    __syncthreads();
  }
  mx = red[0]; __syncthreads();
  float sum = 0.f;
  for (int n = t; n < N; n += 256) {
    float e = expf(rowl[n] - mx);
    rowl[n] = e;
    sum += e;
  }
  red[t] = sum; __syncthreads();
  for (int off = 128; off > 0; off >>= 1) {
    if (t < off) red[t] += red[t + off];
    __syncthreads();
  }
  float scale = (float)N / red[0];
  for (int i = t; i < N / 4; i += 256) {
    float4 v = reinterpret_cast<const float4*>(rowl)[i];
    v.x *= scale; v.y *= scale; v.z *= scale; v.w *= scale;
    reinterpret_cast<float4*>(row)[i] = v;
  }
}

// ---------------- z + scale k by eff*N + RoPE(q,k) in place + write z -------
__global__ __launch_bounds__(256) void k_rope_z(
    float* __restrict__ qkvo, const float* __restrict__ effN,
    const float* __restrict__ kmean, const float* __restrict__ cosT,
    const float* __restrict__ sinT, float* __restrict__ z) {
  int tid = blockIdx.x * 256 + threadIdx.x;   // bpp*N*NH
  int h = tid & 7;
  int bn = tid >> 3;                          // pass-local row
  int n = bn & (N - 1);
  int b = bn >> 12;
  size_t qb = (size_t)bn * C4 + (h << 5);
  float q[32], k[32];
#pragma unroll
  for (int i = 0; i < 8; ++i) {
    float4 q4 = *reinterpret_cast<const float4*>(&qkvo[qb + (i << 2)]);
    float4 k4 = *reinterpret_cast<const float4*>(&qkvo[qb + 256 + (i << 2)]);
    q[i * 4 + 0] = q4.x; q[i * 4 + 1] = q4.y; q[i * 4 + 2] = q4.z; q[i * 4 + 3] = q4.w;
    k[i * 4 + 0] = k4.x; k[i * 4 + 1] = k4.y; k[i * 4 + 2] = k4.z; k[i * 4 + 3] = k4.w;
  }
  int bh = (b << 3) + h;
  const float* km = &kmean[bh << 5];
  float dot = 0.f;
#pragma unroll
  for (int dd = 0; dd < 32; ++dd) dot += q[dd] * km[dd];
  z[(size_t)bh * N + n] = 1.0f / (dot + 1e-6f);
  float ef = effN[(size_t)bh * N + n];
#pragma unroll
  for (int dd = 0; dd < 32; ++dd) k[dd] *= ef;
  const float* cp = &cosT[n << 4];
  const float* sp = &sinT[n << 4];
#pragma unroll
  for (int j = 0; j < 16; ++j) {
    float cc = cp[j], ss = sp[j];
    float qr = q[2 * j], qi = q[2 * j + 1];
    q[2 * j]     = qr * cc - qi * ss;
    q[2 * j + 1] = qr * ss + qi * cc;
    float kr = k[2 * j], ki = k[2 * j + 1];
    k[2 * j]     = kr * cc - ki * ss;
    k[2 * j + 1] = kr * ss + ki * cc;
  }
#pragma unroll
  for (int i = 0; i < 8; ++i) {
    float4 q4 = {q[i * 4 + 0], q[i * 4 + 1], q[i * 4 + 2], q[i * 4 + 3]};
    float4 k4 = {k[i * 4 + 0], k[i * 4 + 1], k[i * 4 + 2], k[i * 4 + 3]};
    *reinterpret_cast<float4*>(&qkvo[qb + (i << 2)]) = q4;
    *reinterpret_cast<float4*>(&qkvo[qb + 256 + (i << 2)]) = k4;
  }
}

// ------------------------- kv partials: per (b,h,chunk) 32x32 outer sum -----
__global__ __launch_bounds__(256) void k_kv_partial(
    const float* __restrict__ qkvo, float* __restrict__ kvp) {
  __shared__ float kt[32][33];
  __shared__ float vt[32][33];
  int bh = blockIdx.x, chunk = blockIdx.y;
  int b = bh >> 3, h = bh & 7;
  int t = threadIdx.x;
  int lrow = t >> 3, lc4 = (t & 7) << 2;
  int d = t >> 3, e0 = (t & 7) << 2;
  float a0 = 0, a1 = 0, a2 = 0, a3 = 0;
  int n_start = chunk << 9;                    // 512 per chunk
  for (int n0 = n_start; n0 < n_start + 512; n0 += 32) {
    size_t g = (size_t)(b * N + n0 + lrow) * C4 + (h << 5) + lc4;
    float4 k4 = *reinterpret_cast<const float4*>(&qkvo[g + 256]);
    float4 v4 = *reinterpret_cast<const float4*>(&qkvo[g + 512]);
    kt[lrow][lc4 + 0] = k4.x; kt[lrow][lc4 + 1] = k4.y;
    kt[lrow][lc4 + 2] = k4.z; kt[lrow][lc4 + 3] = k4.w;
    vt[lrow][lc4 + 0] = v4.x; vt[lrow][lc4 + 1] = v4.y;
    vt[lrow][lc4 + 2] = v4.z; vt[lrow][lc4 + 3] = v4.w;
    __syncthreads();
#pragma unroll
    for (int nn = 0; nn < 32; ++nn) {
      float kd = kt[nn][d];
      a0 = fmaf(kd, vt[nn][e0 + 0], a0);
      a1 = fmaf(kd, vt[nn][e0 + 1], a1);
      a2 = fmaf(kd, vt[nn][e0 + 2], a2);
      a3 = fmaf(kd, vt[nn][e0 + 3], a3);
    }
    __syncthreads();
  }
  size_t o = (size_t)(bh * 8 + chunk) * 1024 + (d << 5) + e0;
  kvp[o + 0] = a0; kvp[o + 1] = a1; kvp[o + 2] = a2; kvp[o + 3] = a3;
}

__global__ void k_kv_reduce(const float* __restrict__ kvp, float* __restrict__ kv,
                            int total) {
  int i = blockIdx.x * 256 + threadIdx.x;     // bpp*NH*1024
  if (i >= total) return;
  int bh = i >> 10, de = i & 1023;
  float s = 0.f;
#pragma unroll
  for (int c = 0; c < 8; ++c) s += kvp[(size_t)(bh * 8 + c) * 1024 + de];
  kv[i] = s * (1.0f / N);                     // fold inv_sqrt_n^2
}

// -------- depthwise 5x5 conv on v (LEPE) -> staged into d_out rows ----------
__global__ __launch_bounds__(256) void k_lepe(
    const float* __restrict__ qkvo, const float* __restrict__ wgt,
    const float* __restrict__ lb, float* __restrict__ lepe_out, int b0) {
  int blk = blockIdx.x;                        // bpp*64*4
  int b = blk >> 8, rem = blk & 255;
  int y = rem >> 2, x0 = (rem & 3) << 4;       // 16 pixels along x
  int c = threadIdx.x;
  float w[25];
#pragma unroll
  for (int i = 0; i < 25; ++i) w[i] = wgt[c * 25 + i];
  float bias = lb[c];
  float acc[16];
#pragma unroll
  for (int p = 0; p < 16; ++p) acc[p] = bias;
#pragma unroll
  for (int dy = 0; dy < 5; ++dy) {
    int yy = y + dy - 2;
    if (yy < 0 || yy >= IH) continue;
    size_t rowb = (size_t)(b * N + (yy << 6)) * C4 + 512 + c;
#pragma unroll
    for (int dx = 0; dx < 5; ++dx) {
      float wv = w[dy * 5 + dx];
#pragma unroll
      for (int p = 0; p < 16; ++p) {
        int xx = x0 + p + dx - 2;
        if (xx < 0 || xx >= IW) continue;
        acc[p] = fmaf(qkvo[rowb + (size_t)xx * C4], wv, acc[p]);
      }
    }
  }
#pragma unroll
  for (int p = 0; p < 16; ++p)
    lepe_out[(size_t)((b0 + b) * N + (y << 6) + x0 + p) * C + c] = acc[p];
}

// ---- opre = ((q_rope @ kv) * z + lepe) * o  -> written into qkvo q-slot ----
__global__ __launch_bounds__(256) void k_out_combine(
    float* __restrict__ qkvo, const float* __restrict__ kv,
    const float* __restrict__ z, const float* __restrict__ lepe, int b0) {
  __shared__ float kvs[1024];
  int bh = blockIdx.x, chunk = blockIdx.y;
  int b = bh >> 3, h = bh & 7;
  int t = threadIdx.x;
  reinterpret_cast<float4*>(kvs)[t] =
      reinterpret_cast<const float4*>(&kv[(size_t)bh << 10])[t];
  __syncthreads();
  int n = (chunk << 8) + t;
  size_t rowbase = (size_t)(b * N + n) * C4;
  float q[32];
#pragma unroll
  for (int i = 0; i < 8; ++i) {
    float4 q4 = *reinterpret_cast<const float4*>(&qkvo[rowbase + (h << 5) + (i << 2)]);
    q[i * 4 + 0] = q4.x; q[i * 4 + 1] = q4.y; q[i * 4 + 2] = q4.z; q[i * 4 + 3] = q4.w;
  }
  float zv = z[(size_t)bh * N + n];
  size_t oc = (size_t)((b0 + b) * N + n) * C + (h << 5);   // lepe rows in d_out
#pragma unroll
  for (int e4 = 0; e4 < 8; ++e4) {
    float ax = 0, ay = 0, az = 0, aw = 0;
#pragma unroll
    for (int dd = 0; dd < 32; ++dd) {
      float4 kv4 = *reinterpret_cast<const float4*>(&kvs[(dd << 5) + (e4 << 2)]);
      float qd = q[dd];
      ax = fmaf(qd, kv4.x, ax); ay = fmaf(qd, kv4.y, ay);
      az = fmaf(qd, kv4.z, az); aw = fmaf(qd, kv4.w, aw);
    }
    float4 lp = *reinterpret_cast<const float4*>(&lepe[oc + (e4 << 2)]);
    float4 ov = *reinterpret_cast<const float4*>(
        &qkvo[rowbase + 768 + (h << 5) + (e4 << 2)]);
    float4 r;
    r.x = (ax * zv + lp.x) * ov.x;
    r.y = (ay * zv + lp.y) * ov.y;
    r.z = (az * zv + lp.z) * ov.z;
    r.w = (aw * zv + lp.w) * ov.w;
    *reinterpret_cast<float4*>(&qkvo[rowbase + (h << 5) + (e4 << 2)]) = r;
  }
}

// ---------------------------------------------------------------------------
static inline size_t ws_floats_needed(int bpp) {
  size_t pn = (size_t)bpp * N;
  return pn * C4                    // qkvo
       + (size_t)bpp * NH * HD * 2  // qmean, kmean
       + (size_t)bpp * NH * N * 2   // eff, z
       + (size_t)bpp * NH * 1024 * 8// kvp
       + (size_t)bpp * NH * 1024    // kv
       + (size_t)bpp * NH * 16 * 32 // colmean partials
       + (size_t)N * 16 * 2;        // cos/sin
}

extern "C" void kernel_launch(void* const* d_in, const int* in_sizes, int n_in,
                              void* d_out, int out_size, void* d_ws, size_t ws_size,
                              hipStream_t stream) {
  const float* x      = (const float*)d_in[0];
  const float* w_qkvo = (const float*)d_in[1];
  const float* b_qkvo = (const float*)d_in[2];
  const float* lepe_w = (const float*)d_in[3];
  const float* lepe_b = (const float*)d_in[4];
  const float* w_proj = (const float*)d_in[5];
  const float* b_proj = (const float*)d_in[6];
  float* out = (float*)d_out;
  float* ws  = (float*)d_ws;

  // pick largest batches-per-pass that fits the workspace
  int bpp = 4;
  if (ws_floats_needed(16) * 4 <= ws_size) bpp = 16;
  else if (ws_floats_needed(8) * 4 <= ws_size) bpp = 8;

  size_t pn = (size_t)bpp * N;
  float* qkvo  = ws;
  float* qmean = qkvo  + pn * C4;
  float* kmean = qmean + (size_t)bpp * NH * HD;
  float* eff   = kmean + (size_t)bpp * NH * HD;
  float* zbuf  = eff   + (size_t)bpp * NH * N;
  float* kvp   = zbuf  + (size_t)bpp * NH * N;
  float* kv    = kvp   + (size_t)bpp * NH * 1024 * 8;
  float* part  = kv    + (size_t)bpp * NH * 1024;
  float* cosT  = part  + (size_t)bpp * NH * 16 * 32;
  float* sinT  = cosT  + (size_t)N * 16;

  k_tables<<<N * 16 / 256, 256, 0, stream>>>(cosT, sinT);

  int nbh = bpp * NH;
  for (int b0 = 0; b0 < B; b0 += bpp) {
    // GEMM1: qkvo = x@w_qkvo + b, elu on cols<512
    k_gemm_mfma<<<dim3(pn / 128, C4 / 128), 256, 0, stream>>>(
        x + (size_t)b0 * N * C, C, w_qkvo, C4, b_qkvo, qkvo, C4, 512);
    k_colmean_part<<<dim3(nbh, 16), 256, 0, stream>>>(qkvo, nullptr, part, 0);
    k_colmean_fin<<<(nbh * 32 + 255) / 256, 256, 0, stream>>>(part, qmean, nbh * 32);
    k_scores<<<(nbh * N) / 256, 256, 0, stream>>>(qkvo, qmean, eff);
    k_softmax<<<nbh, 256, 0, stream>>>(eff);
    k_colmean_part<<<dim3(nbh, 16), 256, 0, stream>>>(qkvo, eff, part, 256);
    k_colmean_fin<<<(nbh * 32 + 255) / 256, 256, 0, stream>>>(part, kmean, nbh * 32);
    k_rope_z<<<(nbh * N) / 256, 256, 0, stream>>>(qkvo, eff, kmean, cosT, sinT, zbuf);
    k_kv_partial<<<dim3(nbh, 8), 256, 0, stream>>>(qkvo, kvp);
    k_kv_reduce<<<(nbh * 1024 + 255) / 256, 256, 0, stream>>>(kvp, kv, nbh * 1024);
    k_lepe<<<bpp * IH * 4, 256, 0, stream>>>(qkvo, lepe_w, lepe_b, out, b0);
    k_out_combine<<<dim3(nbh, N / 256), 256, 0, stream>>>(qkvo, kv, zbuf, out, b0);
    // GEMM2: out = opre @ w_proj + b (opre in qkvo q-slot, stride C4)
    k_gemm_mfma<<<dim3(pn / 128, C / 128), 256, 0, stream>>>(
        qkvo, C4, w_proj, C, b_proj, out + (size_t)b0 * N * C, C, 0);
  }
}